// Round 5
// baseline (1045.312 us; speedup 1.0000x reference)
//
#include <hip/hip_runtime.h>
#include <math.h>

#define TPTS 200000
#define BB 2
#define NPTS (BB*TPTS)
#define HALF TPTS          // batch 0 sorts to slots [0,HALF), batch 1 to [HALF,NPTS)
#define GRID3 32768
#define BG 65536           // BB * GRID3

// cell id: must match reference fp32 arithmetic exactly
__device__ __forceinline__ int cellof(float p0, float p1, float p2, int t)
{
  const float DEN = (float)(1.0 + 0.1 + 1e-3);
  const float HI  = (float)(1.0 - 1e-3);
  float n0 = fminf(fmaxf(p0/DEN + 0.5f, 0.f), HI);
  float n1 = fminf(fmaxf(p1/DEN + 0.5f, 0.f), HI);
  float n2 = fminf(fmaxf(p2/DEN + 0.5f, 0.f), HI);
  int c0 = (int)floorf(n0*32.f), c1 = (int)floorf(n1*32.f), c2 = (int)floorf(n2*32.f);
  return c0 + 32*(c1 + 32*c2) + (t >= TPTS ? GRID3 : 0);
}

__global__ __launch_bounds__(256) void k_hist(
    const float* __restrict__ p, int* __restrict__ gbuf, int* __restrict__ hist)
{
  int t = blockIdx.x*256 + threadIdx.x;
  if (t >= NPTS) return;
  int g = cellof(p[3*t], p[3*t+1], p[3*t+2], t);
  gbuf[t] = g;
  atomicAdd(hist + g, 1);
}

// single-block exclusive scan of hist[BG] -> start[BG+1], cursor[BG]
__global__ __launch_bounds__(1024) void k_scan(
    const int* __restrict__ hist, int* __restrict__ start, int* __restrict__ cursor)
{
  __shared__ int sums[1024];
  const int tid = threadIdx.x;
  const int base = tid * (BG/1024);
  int acc = 0;
#pragma unroll 4
  for (int k = 0; k < BG/1024; k++) acc += hist[base+k];
  sums[tid] = acc;
  __syncthreads();
  for (int off = 1; off < 1024; off <<= 1) {
    int v = sums[tid];
    int u = (tid >= off) ? sums[tid-off] : 0;
    __syncthreads();
    sums[tid] = v + u;
    __syncthreads();
  }
  int run = (tid > 0) ? sums[tid-1] : 0;
#pragma unroll 4
  for (int k = 0; k < BG/1024; k++) {
    start[base+k] = run; cursor[base+k] = run;
    run += hist[base+k];
  }
  if (tid == 1023) start[BG] = sums[1023];
}

// permute raw coords into sorted order
__global__ __launch_bounds__(256) void k_scatter(
    const float* __restrict__ p, const int* __restrict__ gbuf,
    int* __restrict__ cursor, float* __restrict__ p_sorted, int* __restrict__ gsort)
{
  int t = blockIdx.x*256 + threadIdx.x;
  if (t >= NPTS) return;
  int g = gbuf[t];
  int slot = atomicAdd(cursor + g, 1);
  gsort[slot] = g;
  p_sorted[3*slot]   = p[3*t];
  p_sorted[3*slot+1] = p[3*t+1];
  p_sorted[3*slot+2] = p[3*t+2];
}

// posenc + fc_pos -> xbuf (SoA [64][NPTS]); 2 pts/thread; Wp staged in LDS
__global__ __launch_bounds__(256) void k_stage0(
    const float* __restrict__ ps,
    const float* __restrict__ Wp, const float* __restrict__ bp,
    float* __restrict__ xbuf)
{
  __shared__ __align__(16) float s_Wp[3840];
  __shared__ __align__(16) float s_bp[64];
  {
    int t = threadIdx.x;
    for (int idx = t; idx < 3840; idx += 256) s_Wp[idx] = Wp[idx];
    if (t < 64) s_bp[t] = bp[t];
  }
  __syncthreads();
  int i = blockIdx.x*256 + threadIdx.x;
  if (i >= HALF) return;
  int i1 = i + HALF;
  float x0[64], x1[64];
#pragma unroll
  for (int j = 0; j < 64; j++) { float b = s_bp[j]; x0[j] = b; x1[j] = b; }

  float u0[3], u1[3];
  u0[0] = 2.f*ps[3*i]   - 1.f; u0[1] = 2.f*ps[3*i+1]  - 1.f; u0[2] = 2.f*ps[3*i+2]  - 1.f;
  u1[0] = 2.f*ps[3*i1]  - 1.f; u1[1] = 2.f*ps[3*i1+1] - 1.f; u1[2] = 2.f*ps[3*i1+2] - 1.f;
  const float PIF = 3.14159265358979323846f;
#pragma unroll 1
  for (int l = 0; l < 10; l++) {
#pragma unroll
    for (int d = 0; d < 3; d++) {
      float r0 = u0[d] - 2.f*rintf(0.5f*u0[d]);   // exact mod-2 reduction
      float r1 = u1[d] - 2.f*rintf(0.5f*u1[d]);
      float s0, c0, s1, c1;
      __sincosf(PIF*r0, &s0, &c0);
      __sincosf(PIF*r1, &s1, &c1);
      const float* wsr = s_Wp + (l*6 + d)*64;      // sin row
      const float* wcr = s_Wp + (l*6 + 3 + d)*64;  // cos row
#pragma unroll
      for (int j = 0; j < 64; j++) {
        x0[j] = fmaf(s0, wsr[j], fmaf(c0, wcr[j], x0[j]));
        x1[j] = fmaf(s1, wsr[j], fmaf(c1, wcr[j], x1[j]));
      }
      u0[d] *= 2.f; u1[d] *= 2.f;
    }
  }
#pragma unroll
  for (int j = 0; j < 64; j++) {
    xbuf[(size_t)j*NPTS + i]  = x0[j];
    xbuf[(size_t)j*NPTS + i1] = x1[j];
  }
}

// resblock0: K=64 streamed from xbuf; weights in LDS; 2 pts/thread; all accum in regs
__global__ __launch_bounds__(256) void k_res0(
    const float* __restrict__ xbuf,
    const float* __restrict__ w0, const float* __restrict__ b0,
    const float* __restrict__ w1, const float* __restrict__ b1,
    const float* __restrict__ ws,
    float* __restrict__ net)
{
  __shared__ __align__(16) float s_w0[2048], s_ws[2048], s_w1[1024];
  __shared__ __align__(16) float s_b0[32], s_b1[32];
  {
    int t = threadIdx.x;
    for (int idx = t; idx < 2048; idx += 256) { s_w0[idx] = w0[idx]; s_ws[idx] = ws[idx]; }
    for (int idx = t; idx < 1024; idx += 256) s_w1[idx] = w1[idx];
    if (t < 32) { s_b0[t] = b0[t]; s_b1[t] = b1[t]; }
  }
  __syncthreads();
  int i = blockIdx.x*256 + threadIdx.x;
  if (i >= HALF) return;
  int i1 = i + HALF;
  float h0[32], h1[32], y0[32], y1[32];
#pragma unroll
  for (int j = 0; j < 32; j++) {
    float bb0 = s_b0[j], bb1 = s_b1[j];
    h0[j] = bb0; h1[j] = bb0; y0[j] = bb1; y1[j] = bb1;
  }
#pragma unroll 2
  for (int k = 0; k < 64; k++) {
    float a0 = xbuf[(size_t)k*NPTS + i];
    float a1 = xbuf[(size_t)k*NPTS + i1];
    float r0 = fmaxf(a0, 0.f), r1 = fmaxf(a1, 0.f);
#pragma unroll
    for (int j = 0; j < 32; j++) {
      float wa = s_w0[k*32+j], wb = s_ws[k*32+j];
      h0[j] = fmaf(r0, wa, h0[j]); h1[j] = fmaf(r1, wa, h1[j]);
      y0[j] = fmaf(a0, wb, y0[j]); y1[j] = fmaf(a1, wb, y1[j]);
    }
  }
#pragma unroll
  for (int j = 0; j < 32; j++) { h0[j] = fmaxf(h0[j], 0.f); h1[j] = fmaxf(h1[j], 0.f); }
#pragma unroll
  for (int k = 0; k < 32; k++) {
    float v0 = h0[k], v1 = h1[k];
#pragma unroll
    for (int j = 0; j < 32; j++) {
      float w = s_w1[k*32+j];
      y0[j] = fmaf(v0, w, y0[j]); y1[j] = fmaf(v1, w, y1[j]);
    }
  }
#pragma unroll
  for (int j = 0; j < 32; j++) {
    net[(size_t)j*NPTS + i]  = y0[j];
    net[(size_t)j*NPTS + i1] = y1[j];
  }
}

// middle stages: 32 ch from net + 32 pooled; weights in LDS; 2 pts/thread
__global__ __launch_bounds__(256) void k_stage(
    float* __restrict__ net, const int* __restrict__ gsort,
    const float* __restrict__ pooled,
    const float* __restrict__ w0, const float* __restrict__ b0,
    const float* __restrict__ w1, const float* __restrict__ b1,
    const float* __restrict__ ws)
{
  __shared__ __align__(16) float s_w0[2048], s_ws[2048], s_w1[1024];
  __shared__ __align__(16) float s_b0[32], s_b1[32];
  {
    int t = threadIdx.x;
    for (int idx = t; idx < 2048; idx += 256) { s_w0[idx] = w0[idx]; s_ws[idx] = ws[idx]; }
    for (int idx = t; idx < 1024; idx += 256) s_w1[idx] = w1[idx];
    if (t < 32) { s_b0[t] = b0[t]; s_b1[t] = b1[t]; }
  }
  __syncthreads();
  int i = blockIdx.x*256 + threadIdx.x;
  if (i >= HALF) return;
  int i1 = i + HALF;
  int g0 = gsort[i], g1 = gsort[i1];
  float h0[32], h1[32], y0[32], y1[32];
#pragma unroll
  for (int j = 0; j < 32; j++) {
    float bb0 = s_b0[j], bb1 = s_b1[j];
    h0[j] = bb0; h1[j] = bb0; y0[j] = bb1; y1[j] = bb1;
  }
#pragma unroll 2
  for (int k = 0; k < 32; k++) {
    float a0 = net[(size_t)k*NPTS + i];
    float a1 = net[(size_t)k*NPTS + i1];
    float r0 = fmaxf(a0, 0.f), r1 = fmaxf(a1, 0.f);
#pragma unroll
    for (int j = 0; j < 32; j++) {
      float wa = s_w0[k*32+j], wb = s_ws[k*32+j];
      h0[j] = fmaf(r0, wa, h0[j]); h1[j] = fmaf(r1, wa, h1[j]);
      y0[j] = fmaf(a0, wb, y0[j]); y1[j] = fmaf(a1, wb, y1[j]);
    }
  }
#pragma unroll 2
  for (int k = 0; k < 32; k++) {
    float a0 = pooled[(size_t)k*BG + g0];
    float a1 = pooled[(size_t)k*BG + g1];
    float r0 = fmaxf(a0, 0.f), r1 = fmaxf(a1, 0.f);
#pragma unroll
    for (int j = 0; j < 32; j++) {
      float wa = s_w0[(32+k)*32+j], wb = s_ws[(32+k)*32+j];
      h0[j] = fmaf(r0, wa, h0[j]); h1[j] = fmaf(r1, wa, h1[j]);
      y0[j] = fmaf(a0, wb, y0[j]); y1[j] = fmaf(a1, wb, y1[j]);
    }
  }
#pragma unroll
  for (int j = 0; j < 32; j++) { h0[j] = fmaxf(h0[j], 0.f); h1[j] = fmaxf(h1[j], 0.f); }
#pragma unroll
  for (int k = 0; k < 32; k++) {
    float v0 = h0[k], v1 = h1[k];
#pragma unroll
    for (int j = 0; j < 32; j++) {
      float w = s_w1[k*32+j];
      y0[j] = fmaf(v0, w, y0[j]); y1[j] = fmaf(v1, w, y1[j]);
    }
  }
#pragma unroll
  for (int j = 0; j < 32; j++) {
    net[(size_t)j*NPTS + i]  = y0[j];
    net[(size_t)j*NPTS + i1] = y1[j];
  }
}

// last stage + fc_c, all in registers; weights in LDS; 2 pts/thread
__global__ __launch_bounds__(256) void k_final(
    float* __restrict__ net, const int* __restrict__ gsort,
    const float* __restrict__ pooled,
    const float* __restrict__ w0, const float* __restrict__ b0,
    const float* __restrict__ w1, const float* __restrict__ b1,
    const float* __restrict__ ws,
    const float* __restrict__ wc, const float* __restrict__ bc)
{
  __shared__ __align__(16) float s_w0[2048], s_ws[2048], s_w1[1024], s_wc[1024];
  __shared__ __align__(16) float s_b0[32], s_b1[32], s_bc[32];
  {
    int t = threadIdx.x;
    for (int idx = t; idx < 2048; idx += 256) { s_w0[idx] = w0[idx]; s_ws[idx] = ws[idx]; }
    for (int idx = t; idx < 1024; idx += 256) { s_w1[idx] = w1[idx]; s_wc[idx] = wc[idx]; }
    if (t < 32) { s_b0[t] = b0[t]; s_b1[t] = b1[t]; s_bc[t] = bc[t]; }
  }
  __syncthreads();
  int i = blockIdx.x*256 + threadIdx.x;
  if (i >= HALF) return;
  int i1 = i + HALF;
  int g0 = gsort[i], g1 = gsort[i1];
  float h0[32], h1[32], y0[32], y1[32];
#pragma unroll
  for (int j = 0; j < 32; j++) {
    float bb0 = s_b0[j], bb1 = s_b1[j];
    h0[j] = bb0; h1[j] = bb0; y0[j] = bb1; y1[j] = bb1;
  }
#pragma unroll 2
  for (int k = 0; k < 32; k++) {
    float a0 = net[(size_t)k*NPTS + i];
    float a1 = net[(size_t)k*NPTS + i1];
    float r0 = fmaxf(a0, 0.f), r1 = fmaxf(a1, 0.f);
#pragma unroll
    for (int j = 0; j < 32; j++) {
      float wa = s_w0[k*32+j], wb = s_ws[k*32+j];
      h0[j] = fmaf(r0, wa, h0[j]); h1[j] = fmaf(r1, wa, h1[j]);
      y0[j] = fmaf(a0, wb, y0[j]); y1[j] = fmaf(a1, wb, y1[j]);
    }
  }
#pragma unroll 2
  for (int k = 0; k < 32; k++) {
    float a0 = pooled[(size_t)k*BG + g0];
    float a1 = pooled[(size_t)k*BG + g1];
    float r0 = fmaxf(a0, 0.f), r1 = fmaxf(a1, 0.f);
#pragma unroll
    for (int j = 0; j < 32; j++) {
      float wa = s_w0[(32+k)*32+j], wb = s_ws[(32+k)*32+j];
      h0[j] = fmaf(r0, wa, h0[j]); h1[j] = fmaf(r1, wa, h1[j]);
      y0[j] = fmaf(a0, wb, y0[j]); y1[j] = fmaf(a1, wb, y1[j]);
    }
  }
#pragma unroll
  for (int j = 0; j < 32; j++) { h0[j] = fmaxf(h0[j], 0.f); h1[j] = fmaxf(h1[j], 0.f); }
#pragma unroll
  for (int k = 0; k < 32; k++) {
    float v0 = h0[k], v1 = h1[k];
#pragma unroll
    for (int j = 0; j < 32; j++) {
      float w = s_w1[k*32+j];
      y0[j] = fmaf(v0, w, y0[j]); y1[j] = fmaf(v1, w, y1[j]);
    }
  }
  // fc_c straight from registers (h0/h1 dead -> reuse their registers for c)
  float c0[32], c1[32];
#pragma unroll
  for (int j = 0; j < 32; j++) { float b = s_bc[j]; c0[j] = b; c1[j] = b; }
#pragma unroll
  for (int k = 0; k < 32; k++) {
    float v0 = y0[k], v1 = y1[k];
#pragma unroll
    for (int j = 0; j < 32; j++) {
      float w = s_wc[k*32+j];
      c0[j] = fmaf(v0, w, c0[j]); c1[j] = fmaf(v1, w, c1[j]);
    }
  }
#pragma unroll
  for (int j = 0; j < 32; j++) {
    net[(size_t)j*NPTS + i]  = c0[j];
    net[(size_t)j*NPTS + i1] = c1[j];
  }
}

// per (ch, cell) max over the cell's contiguous range; cell fastest -> coalesced
__global__ __launch_bounds__(256) void k_pool(
    const float* __restrict__ net, const int* __restrict__ start,
    float* __restrict__ pooled)
{
  int tid = blockIdx.x*256 + threadIdx.x;   // [0, 32*BG)
  int c = tid & (BG-1), ch = tid >> 16;
  int s = start[c], e = start[c+1];
  const float* base = net + (size_t)ch*NPTS;
  float m = -INFINITY;
  for (int k = s; k < e; k++) m = fmaxf(m, base[k]);
  pooled[(size_t)ch*BG + c] = m;
}

// per (ch, cell) mean -> out[b][ch][cell]; empty cells -> 0
__global__ __launch_bounds__(256) void k_mean(
    const float* __restrict__ net, const int* __restrict__ start,
    float* __restrict__ outp)
{
  int tid = blockIdx.x*256 + threadIdx.x;
  int c = tid & (BG-1), ch = tid >> 16;
  int s = start[c], e = start[c+1];
  const float* base = net + (size_t)ch*NPTS;
  float sum = 0.f;
  for (int k = s; k < e; k++) sum += base[k];
  float v = (e > s) ? sum / (float)(e - s) : 0.f;
  int b = c >> 15, cell = c & 32767;
  outp[((size_t)b << 20) + ((size_t)ch << 15) + cell] = v;
}

extern "C" void kernel_launch(void* const* d_in, const int* in_sizes, int n_in,
                              void* d_out, int out_size, void* d_ws, size_t ws_size,
                              hipStream_t stream)
{
  const float* p   = (const float*)d_in[0];
  const float* Wp  = (const float*)d_in[1];
  const float* bp  = (const float*)d_in[2];
  const float* f0w = (const float*)d_in[3];
  const float* f0b = (const float*)d_in[4];
  const float* f1w = (const float*)d_in[5];
  const float* f1b = (const float*)d_in[6];
  const float* scw = (const float*)d_in[7];
  const float* wc  = (const float*)d_in[8];
  const float* bc  = (const float*)d_in[9];
  float* outp = (float*)d_out;

  char* wsb = (char*)d_ws;
  float* net      = (float*)wsb;                         // NPTS*32 f32 = 51.2 MB
  int*   gbuf     = (int*)(net + (size_t)NPTS*32);       // NPTS
  int*   gsort    = gbuf + NPTS;                         // NPTS
  int*   hist     = gsort + NPTS;                        // BG
  int*   start    = hist + BG;                           // BG+1
  int*   cursor   = start + BG + 1;                      // BG
  float* p_sorted = (float*)(cursor + BG);               // NPTS*3
  float* xbuf     = p_sorted + (size_t)NPTS*3;           // NPTS*64 f32 = 102.4 MB
  float* pooled   = xbuf;                                // aliases xbuf (dead after k_res0)

  dim3 blk(256);
  dim3 gpts((NPTS + 255)/256);
  dim3 ghalf((HALF + 255)/256);
  dim3 gcell((BG*32)/256);

  hipMemsetAsync(hist, 0, (size_t)BG*4, stream);
  hipLaunchKernelGGL(k_hist, gpts, blk, 0, stream, p, gbuf, hist);
  hipLaunchKernelGGL(k_scan, dim3(1), dim3(1024), 0, stream, hist, start, cursor);
  hipLaunchKernelGGL(k_scatter, gpts, blk, 0, stream, p, gbuf, cursor, p_sorted, gsort);
  hipLaunchKernelGGL(k_stage0, ghalf, blk, 0, stream, p_sorted, Wp, bp, xbuf);
  hipLaunchKernelGGL(k_res0, ghalf, blk, 0, stream,
                     xbuf, f0w, f0b, f1w, f1b, scw, net);
  hipLaunchKernelGGL(k_pool, gcell, blk, 0, stream, net, start, pooled);
  hipLaunchKernelGGL(k_stage, ghalf, blk, 0, stream, net, gsort, pooled,
                     f0w + 1*2048, f0b + 1*32, f1w + 1*1024, f1b + 1*32, scw + 1*2048);
  hipLaunchKernelGGL(k_pool, gcell, blk, 0, stream, net, start, pooled);
  hipLaunchKernelGGL(k_stage, ghalf, blk, 0, stream, net, gsort, pooled,
                     f0w + 2*2048, f0b + 2*32, f1w + 2*1024, f1b + 2*32, scw + 2*2048);
  hipLaunchKernelGGL(k_pool, gcell, blk, 0, stream, net, start, pooled);
  hipLaunchKernelGGL(k_stage, ghalf, blk, 0, stream, net, gsort, pooled,
                     f0w + 3*2048, f0b + 3*32, f1w + 3*1024, f1b + 3*32, scw + 3*2048);
  hipLaunchKernelGGL(k_pool, gcell, blk, 0, stream, net, start, pooled);
  hipLaunchKernelGGL(k_final, ghalf, blk, 0, stream, net, gsort, pooled,
                     f0w + 4*2048, f0b + 4*32, f1w + 4*1024, f1b + 4*32, scw + 4*2048,
                     wc, bc);
  hipLaunchKernelGGL(k_mean, gcell, blk, 0, stream, net, start, outp);
}

// Round 6
// 643.221 us; speedup vs baseline: 1.6251x; 1.6251x over previous
//
#include <hip/hip_runtime.h>
#include <math.h>

#define TPTS 200000
#define BB 2
#define NPTS (BB*TPTS)
#define GRID3 32768
#define BG 65536   // BB * GRID3

// cell id: must match reference fp32 arithmetic exactly
__device__ __forceinline__ int cellof(float p0, float p1, float p2, int t)
{
  const float DEN = (float)(1.0 + 0.1 + 1e-3);
  const float HI  = (float)(1.0 - 1e-3);
  float n0 = fminf(fmaxf(p0/DEN + 0.5f, 0.f), HI);
  float n1 = fminf(fmaxf(p1/DEN + 0.5f, 0.f), HI);
  float n2 = fminf(fmaxf(p2/DEN + 0.5f, 0.f), HI);
  int c0 = (int)floorf(n0*32.f), c1 = (int)floorf(n1*32.f), c2 = (int)floorf(n2*32.f);
  return c0 + 32*(c1 + 32*c2) + (t >= TPTS ? GRID3 : 0);
}

__global__ __launch_bounds__(256) void k_hist(
    const float* __restrict__ p, int* __restrict__ gbuf, int* __restrict__ hist)
{
  int t = blockIdx.x*256 + threadIdx.x;
  if (t >= NPTS) return;
  int g = cellof(p[3*t], p[3*t+1], p[3*t+2], t);
  gbuf[t] = g;
  atomicAdd(hist + g, 1);
}

// single-block exclusive scan of hist[BG] -> start[BG+1], cursor[BG]
__global__ __launch_bounds__(1024) void k_scan(
    const int* __restrict__ hist, int* __restrict__ start, int* __restrict__ cursor)
{
  __shared__ int sums[1024];
  const int tid = threadIdx.x;
  const int base = tid * (BG/1024);
  int acc = 0;
#pragma unroll 4
  for (int k = 0; k < BG/1024; k++) acc += hist[base+k];
  sums[tid] = acc;
  __syncthreads();
  for (int off = 1; off < 1024; off <<= 1) {
    int v = sums[tid];
    int u = (tid >= off) ? sums[tid-off] : 0;
    __syncthreads();
    sums[tid] = v + u;
    __syncthreads();
  }
  int run = (tid > 0) ? sums[tid-1] : 0;
#pragma unroll 4
  for (int k = 0; k < BG/1024; k++) {
    start[base+k] = run; cursor[base+k] = run;
    run += hist[base+k];
  }
  if (tid == 1023) start[BG] = sums[1023];
}

// permute raw coords into sorted order
__global__ __launch_bounds__(256) void k_scatter(
    const float* __restrict__ p, const int* __restrict__ gbuf,
    int* __restrict__ cursor, float* __restrict__ p_sorted, int* __restrict__ gsort)
{
  int t = blockIdx.x*256 + threadIdx.x;
  if (t >= NPTS) return;
  int g = gbuf[t];
  int slot = atomicAdd(cursor + g, 1);
  gsort[slot] = g;
  p_sorted[3*slot]   = p[3*t];
  p_sorted[3*slot+1] = p[3*t+1];
  p_sorted[3*slot+2] = p[3*t+2];
}

// posenc + fc_pos -> xbuf (SoA [64][NPTS]), sorted order, rolled l-loop
__global__ __launch_bounds__(256) void k_stage0(
    const float* __restrict__ ps,
    const float* __restrict__ Wp, const float* __restrict__ bp,
    float* __restrict__ xbuf)
{
  int i = blockIdx.x*256 + threadIdx.x;
  if (i >= NPTS) return;
  float p0 = ps[3*i], p1 = ps[3*i+1], p2 = ps[3*i+2];

  float x[64];
#pragma unroll
  for (int j = 0; j < 64; j++) x[j] = bp[j];

  float u0 = 2.f*p0 - 1.f, u1 = 2.f*p1 - 1.f, u2 = 2.f*p2 - 1.f;
  const float PIF = 3.14159265358979323846f;
#pragma unroll 1
  for (int l = 0; l < 10; l++) {
    float uu[3] = {u0, u1, u2};
#pragma unroll
    for (int d = 0; d < 3; d++) {
      float r = uu[d] - 2.f*rintf(0.5f*uu[d]);   // exact mod-2 reduction
      float s, c;
      __sincosf(PIF*r, &s, &c);
      const float* wsr = Wp + (l*6 + d)*64;      // sin row
      const float* wcr = Wp + (l*6 + 3 + d)*64;  // cos row
#pragma unroll
      for (int j = 0; j < 64; j++) x[j] = fmaf(s, wsr[j], fmaf(c, wcr[j], x[j]));
    }
    u0 *= 2.f; u1 *= 2.f; u2 *= 2.f;
  }
#pragma unroll
  for (int j = 0; j < 64; j++) xbuf[(size_t)j*NPTS + i] = x[j];
}

// resblock0: K=64 streamed from xbuf, unroll 8 (deep MLP), s_load weights
__global__ __launch_bounds__(256) void k_res0(
    const float* __restrict__ xbuf,
    const float* __restrict__ w0, const float* __restrict__ b0,
    const float* __restrict__ w1, const float* __restrict__ b1,
    const float* __restrict__ ws,
    float* __restrict__ net)
{
  int i = blockIdx.x*256 + threadIdx.x;
  if (i >= NPTS) return;
  float h[32], y[32];
#pragma unroll
  for (int j = 0; j < 32; j++) { h[j] = b0[j]; y[j] = b1[j]; }
#pragma unroll 8
  for (int k = 0; k < 64; k++) {
    float xv = xbuf[(size_t)k*NPTS + i];
    float xr = fmaxf(xv, 0.f);
    const float* w0r = w0 + k*32;
    const float* wsr = ws + k*32;
#pragma unroll
    for (int j = 0; j < 32; j++) {
      h[j] = fmaf(xr, w0r[j], h[j]);
      y[j] = fmaf(xv, wsr[j], y[j]);
    }
  }
#pragma unroll
  for (int j = 0; j < 32; j++) h[j] = fmaxf(h[j], 0.f);
#pragma unroll
  for (int k = 0; k < 32; k++) {
    float hv = h[k];
#pragma unroll
    for (int j = 0; j < 32; j++) y[j] = fmaf(hv, w1[k*32+j], y[j]);
  }
#pragma unroll
  for (int j = 0; j < 32; j++) net[(size_t)j*NPTS + i] = y[j];
}

// middle stages: own 32 ch from net (coalesced) + pooled 32 ch; unroll 8
__global__ __launch_bounds__(256) void k_stage(
    float* __restrict__ net, const int* __restrict__ gsort,
    const float* __restrict__ pooled,
    const float* __restrict__ w0, const float* __restrict__ b0,
    const float* __restrict__ w1, const float* __restrict__ b1,
    const float* __restrict__ ws)
{
  int i = blockIdx.x*256 + threadIdx.x;
  if (i >= NPTS) return;
  int g = gsort[i];
  float h[32], y[32];
#pragma unroll
  for (int j = 0; j < 32; j++) { h[j] = b0[j]; y[j] = b1[j]; }
#pragma unroll 8
  for (int k = 0; k < 32; k++) {
    float xv = net[(size_t)k*NPTS + i];
    float xr = fmaxf(xv, 0.f);
    const float* w0r = w0 + k*32;
    const float* wsr = ws + k*32;
#pragma unroll
    for (int j = 0; j < 32; j++) {
      h[j] = fmaf(xr, w0r[j], h[j]);
      y[j] = fmaf(xv, wsr[j], y[j]);
    }
  }
#pragma unroll 8
  for (int k = 0; k < 32; k++) {
    float xv = pooled[(size_t)k*BG + g];
    float xr = fmaxf(xv, 0.f);
    const float* w0r = w0 + (32+k)*32;
    const float* wsr = ws + (32+k)*32;
#pragma unroll
    for (int j = 0; j < 32; j++) {
      h[j] = fmaf(xr, w0r[j], h[j]);
      y[j] = fmaf(xv, wsr[j], y[j]);
    }
  }
#pragma unroll
  for (int j = 0; j < 32; j++) h[j] = fmaxf(h[j], 0.f);
#pragma unroll
  for (int k = 0; k < 32; k++) {
    float hv = h[k];
#pragma unroll
    for (int j = 0; j < 32; j++) y[j] = fmaf(hv, w1[k*32+j], y[j]);
  }
#pragma unroll
  for (int j = 0; j < 32; j++) net[(size_t)j*NPTS + i] = y[j];
}

// last stage + fc_c, fc_c from registers (no net round-trip); stores only c
__global__ __launch_bounds__(256) void k_final(
    float* __restrict__ net, const int* __restrict__ gsort,
    const float* __restrict__ pooled,
    const float* __restrict__ w0, const float* __restrict__ b0,
    const float* __restrict__ w1, const float* __restrict__ b1,
    const float* __restrict__ ws,
    const float* __restrict__ wc, const float* __restrict__ bc)
{
  int i = blockIdx.x*256 + threadIdx.x;
  if (i >= NPTS) return;
  int g = gsort[i];
  float h[32], y[32];
#pragma unroll
  for (int j = 0; j < 32; j++) { h[j] = b0[j]; y[j] = b1[j]; }
#pragma unroll 8
  for (int k = 0; k < 32; k++) {
    float xv = net[(size_t)k*NPTS + i];
    float xr = fmaxf(xv, 0.f);
    const float* w0r = w0 + k*32;
    const float* wsr = ws + k*32;
#pragma unroll
    for (int j = 0; j < 32; j++) {
      h[j] = fmaf(xr, w0r[j], h[j]);
      y[j] = fmaf(xv, wsr[j], y[j]);
    }
  }
#pragma unroll 8
  for (int k = 0; k < 32; k++) {
    float xv = pooled[(size_t)k*BG + g];
    float xr = fmaxf(xv, 0.f);
    const float* w0r = w0 + (32+k)*32;
    const float* wsr = ws + (32+k)*32;
#pragma unroll
    for (int j = 0; j < 32; j++) {
      h[j] = fmaf(xr, w0r[j], h[j]);
      y[j] = fmaf(xv, wsr[j], y[j]);
    }
  }
#pragma unroll
  for (int j = 0; j < 32; j++) h[j] = fmaxf(h[j], 0.f);
#pragma unroll
  for (int k = 0; k < 32; k++) {
    float hv = h[k];
#pragma unroll
    for (int j = 0; j < 32; j++) y[j] = fmaf(hv, w1[k*32+j], y[j]);
  }
  // fc_c straight from registers (h dead -> register reuse)
  float c[32];
#pragma unroll
  for (int j = 0; j < 32; j++) c[j] = bc[j];
#pragma unroll
  for (int k = 0; k < 32; k++) {
    float yv = y[k];
#pragma unroll
    for (int j = 0; j < 32; j++) c[j] = fmaf(yv, wc[k*32+j], c[j]);
  }
#pragma unroll
  for (int j = 0; j < 32; j++) net[(size_t)j*NPTS + i] = c[j];
}

// per (ch, cell) max over the cell's contiguous range; cell fastest -> coalesced
__global__ __launch_bounds__(256) void k_pool(
    const float* __restrict__ net, const int* __restrict__ start,
    float* __restrict__ pooled)
{
  int tid = blockIdx.x*256 + threadIdx.x;   // [0, 32*BG)
  int c = tid & (BG-1), ch = tid >> 16;
  int s = start[c], e = start[c+1];
  const float* base = net + (size_t)ch*NPTS;
  float m = -INFINITY;
  for (int k = s; k < e; k++) m = fmaxf(m, base[k]);
  pooled[(size_t)ch*BG + c] = m;
}

// per (ch, cell) mean -> out[b][ch][cell]; empty cells -> 0
__global__ __launch_bounds__(256) void k_mean(
    const float* __restrict__ net, const int* __restrict__ start,
    float* __restrict__ outp)
{
  int tid = blockIdx.x*256 + threadIdx.x;
  int c = tid & (BG-1), ch = tid >> 16;
  int s = start[c], e = start[c+1];
  const float* base = net + (size_t)ch*NPTS;
  float sum = 0.f;
  for (int k = s; k < e; k++) sum += base[k];
  float v = (e > s) ? sum / (float)(e - s) : 0.f;
  int b = c >> 15, cell = c & 32767;
  outp[((size_t)b << 20) + ((size_t)ch << 15) + cell] = v;
}

extern "C" void kernel_launch(void* const* d_in, const int* in_sizes, int n_in,
                              void* d_out, int out_size, void* d_ws, size_t ws_size,
                              hipStream_t stream)
{
  const float* p   = (const float*)d_in[0];
  const float* Wp  = (const float*)d_in[1];
  const float* bp  = (const float*)d_in[2];
  const float* f0w = (const float*)d_in[3];
  const float* f0b = (const float*)d_in[4];
  const float* f1w = (const float*)d_in[5];
  const float* f1b = (const float*)d_in[6];
  const float* scw = (const float*)d_in[7];
  const float* wc  = (const float*)d_in[8];
  const float* bc  = (const float*)d_in[9];
  float* outp = (float*)d_out;

  char* wsb = (char*)d_ws;
  float* net      = (float*)wsb;                         // NPTS*32 f32 = 51.2 MB
  int*   gbuf     = (int*)(net + (size_t)NPTS*32);       // NPTS
  int*   gsort    = gbuf + NPTS;                         // NPTS
  int*   hist     = gsort + NPTS;                        // BG
  int*   start    = hist + BG;                           // BG+1
  int*   cursor   = start + BG + 1;                      // BG
  float* p_sorted = (float*)(cursor + BG);               // NPTS*3
  float* xbuf     = p_sorted + (size_t)NPTS*3;           // NPTS*64 f32 = 102.4 MB
  float* pooled   = xbuf;                                // aliases xbuf (dead after k_res0)

  dim3 blk(256);
  dim3 gpts((NPTS + 255)/256);
  dim3 gcell((BG*32)/256);

  hipMemsetAsync(hist, 0, (size_t)BG*4, stream);
  hipLaunchKernelGGL(k_hist, gpts, blk, 0, stream, p, gbuf, hist);
  hipLaunchKernelGGL(k_scan, dim3(1), dim3(1024), 0, stream, hist, start, cursor);
  hipLaunchKernelGGL(k_scatter, gpts, blk, 0, stream, p, gbuf, cursor, p_sorted, gsort);
  hipLaunchKernelGGL(k_stage0, gpts, blk, 0, stream, p_sorted, Wp, bp, xbuf);
  hipLaunchKernelGGL(k_res0, gpts, blk, 0, stream,
                     xbuf, f0w, f0b, f1w, f1b, scw, net);
  hipLaunchKernelGGL(k_pool, gcell, blk, 0, stream, net, start, pooled);
  hipLaunchKernelGGL(k_stage, gpts, blk, 0, stream, net, gsort, pooled,
                     f0w + 1*2048, f0b + 1*32, f1w + 1*1024, f1b + 1*32, scw + 1*2048);
  hipLaunchKernelGGL(k_pool, gcell, blk, 0, stream, net, start, pooled);
  hipLaunchKernelGGL(k_stage, gpts, blk, 0, stream, net, gsort, pooled,
                     f0w + 2*2048, f0b + 2*32, f1w + 2*1024, f1b + 2*32, scw + 2*2048);
  hipLaunchKernelGGL(k_pool, gcell, blk, 0, stream, net, start, pooled);
  hipLaunchKernelGGL(k_stage, gpts, blk, 0, stream, net, gsort, pooled,
                     f0w + 3*2048, f0b + 3*32, f1w + 3*1024, f1b + 3*32, scw + 3*2048);
  hipLaunchKernelGGL(k_pool, gcell, blk, 0, stream, net, start, pooled);
  hipLaunchKernelGGL(k_final, gpts, blk, 0, stream, net, gsort, pooled,
                     f0w + 4*2048, f0b + 4*32, f1w + 4*1024, f1b + 4*32, scw + 4*2048,
                     wc, bc);
  hipLaunchKernelGGL(k_mean, gcell, blk, 0, stream, net, start, outp);
}